// Round 9
// baseline (1591.539 us; speedup 1.0000x reference)
//
#include <hip/hip_runtime.h>
#include <math.h>

#define TPB 256

// ---------------------------------------------------------------------------
// Geometry:
//   x: [8, 1, 128, 1024] f32
//   L0: CI=1,  CO=16, 128x1024, pool -> 64x512   (fused offsets)
//   L1: CI=16, CO=32, 64x512,   pool -> 32x256
//   L2: CI=32, CO=48, 32x256,   pool -> 16x128
//   L3: CI=48, CO=64, 16x128,   no pool
//   L4: CI=64, CO=80, 16x128,   no pool -> d_out
//
// R9: dfc_lds — two-phase deform conv.
//   Phase B: thread=(pixel,slice): S=CI/4 consecutive lanes read contiguous
//     float4s per corner (full cache-line use; R8's lane-stride-CI gathers
//     used ~1/8 of each line). Samples staged per-tap in LDS.
//   Phase C: thread=(pixel, wave-uniform og): ds_read_b128 -> 4*COG FMAs,
//     weights via s_load. All og groups per block -> corners gathered ONCE
//     (R8 re-gathered x OGC). Per-tap double-buffered LDS, 1 barrier/tap.
// Kept: NHWC activations, wave-uniform packed weights, XCD swizzle,
// no launch_bounds min-wave cap, bounded register footprints.
// ---------------------------------------------------------------------------

// Packed-weight workspace offsets (floats)
#define OWM0 0
#define OWM1 144
#define OWM2 4752
#define OWM3 18576
#define OWM4 46224
#define OWO0 92304
#define OWO1 92484
#define OWO2 95940
#define OWO3 102852
#define OWO4 113220
#define PACK_FLOATS 131072

struct PackSrc { const float* p[10]; };  // 0-4: wmain, 5-9: woff

__global__ void pack_weights(PackSrc s, float* __restrict__ dst) {
  int seg = blockIdx.y;
  int idx = blockIdx.x * TPB + threadIdx.x;
  int CI, CO, ow;
  if (seg < 5) {
    if (seg == 0)      { CI = 1;  CO = 16; ow = OWM0; }
    else if (seg == 1) { CI = 16; CO = 32; ow = OWM1; }
    else if (seg == 2) { CI = 32; CO = 48; ow = OWM2; }
    else if (seg == 3) { CI = 48; CO = 64; ow = OWM3; }
    else               { CI = 64; CO = 80; ow = OWM4; }
    int n = 9 * CI * CO;
    if (idx >= n) return;
    int o = idx % CO, rest = idx / CO;
    int c = rest % CI, k = rest / CI;
    dst[ow + idx] = s.p[seg][((size_t)o * CI + c) * 9 + k];
  } else if (seg == 5) {
    if (idx >= 180) return;
    int j = idx % 20, t = idx / 20;
    dst[OWO0 + idx] = (j < 18) ? s.p[5][j * 9 + t] : 0.f;
  } else {
    if (seg == 6)      { CI = 16; ow = OWO1; }
    else if (seg == 7) { CI = 32; ow = OWO2; }
    else if (seg == 8) { CI = 48; ow = OWO3; }
    else               { CI = 64; ow = OWO4; }
    int n = 3 * CI * 9 * 8;
    if (idx >= n) return;
    int u = idx % 8, r = idx / 8;
    int t = r % 9, c = (r / 9) % CI, jg = r / (9 * CI);
    dst[ow + idx] = (u < 6) ? s.p[seg][((size_t)(jg * 6 + u) * CI + c) * 9 + t] : 0.f;
  }
}

// XCD-aware swizzle: nwg % 8 == 0 at every launch site.
__device__ __forceinline__ int xcd_swz(int bid, int nwg) {
  return (bid & 7) * (nwg >> 3) + (bid >> 3);
}

// ---------------------------------------------------------------------------
// L0: CI=1 (NCHW==NHWC) -> fused offsets + deform conv, out NCHW.
// ---------------------------------------------------------------------------
__global__ __launch_bounds__(TPB) void dfc_fused0(
    const float* __restrict__ x, const float* __restrict__ woP,   // [9][20]
    const float* __restrict__ boff, const float* __restrict__ wmP, // [9][16]
    float* __restrict__ out, int B, int H, int W) {
  const int idx = xcd_swz(blockIdx.x, gridDim.x) * TPB + threadIdx.x;
  const int HW = H * W;
  const int w = idx % W;
  const int h = (idx / W) % H;
  const int b = idx / HW;
  const float* xp = x + (size_t)b * HW;

  float xv[9];
#pragma unroll
  for (int t = 0; t < 9; t++) {
    int yy = h - 1 + t / 3, xx = w - 1 + t % 3;
    xv[t] = (yy >= 0 && yy < H && xx >= 0 && xx < W) ? xp[yy * W + xx] : 0.f;
  }

  float offv[18];
#pragma unroll
  for (int j = 0; j < 18; j++) offv[j] = boff[j];
#pragma unroll
  for (int t = 0; t < 9; t++) {
    const float* wr = &woP[t * 20];
#pragma unroll
    for (int j = 0; j < 18; j++) offv[j] = fmaf(xv[t], wr[j], offv[j]);
  }

  float acc[16];
#pragma unroll
  for (int o = 0; o < 16; o++) acc[o] = 0.f;

#pragma unroll
  for (int k = 0; k < 9; k++) {
    float py = (float)(h - 1 + k / 3) + offv[2 * k];
    float px = (float)(w - 1 + k % 3) + offv[2 * k + 1];
    float fy = floorf(py), fx = floorf(px);
    float wy = py - fy, wx = px - fx;
    int y0 = (int)fy, x0 = (int)fx;
    int y1 = y0 + 1, x1 = x0 + 1;
    bool vy0 = (y0 >= 0) & (y0 < H), vy1 = (y1 >= 0) & (y1 < H);
    bool vx0 = (x0 >= 0) & (x0 < W), vx1 = (x1 >= 0) & (x1 < W);
    int yc0 = min(max(y0, 0), H - 1), yc1 = min(max(y1, 0), H - 1);
    int xc0 = min(max(x0, 0), W - 1), xc1 = min(max(x1, 0), W - 1);
    float w00 = (vy0 && vx0) ? (1.f - wy) * (1.f - wx) : 0.f;
    float w01 = (vy0 && vx1) ? (1.f - wy) * wx : 0.f;
    float w10 = (vy1 && vx0) ? wy * (1.f - wx) : 0.f;
    float w11 = (vy1 && vx1) ? wy * wx : 0.f;
    float sv = xp[yc0 * W + xc0] * w00 + xp[yc0 * W + xc1] * w01
             + xp[yc1 * W + xc0] * w10 + xp[yc1 * W + xc1] * w11;
    const float* wr = &wmP[k * 16];
#pragma unroll
    for (int o = 0; o < 16; o++) acc[o] = fmaf(sv, wr[o], acc[o]);
  }

  float* op = out + (size_t)b * 16 * HW + h * W + w;
#pragma unroll
  for (int o = 0; o < 16; o++) op[(size_t)o * HW] = acc[o];
}

// ---------------------------------------------------------------------------
// Offset conv (L1-L4): x NHWC, per tap CI/4 float4 loads, s_load weights.
// ---------------------------------------------------------------------------
template<int CI, int TPBK>
__global__ __launch_bounds__(TPBK) void off_conv(
    const float* __restrict__ x, const float* __restrict__ wP,
    const float* __restrict__ boff, float* __restrict__ off,
    int B, int H, int W) {
  const int HW = H * W;
  const int npb = HW / TPBK;
  const int bid = xcd_swz(blockIdx.x, gridDim.x);
  const int pxb = bid % npb;
  const int jg = (bid / npb) % 3;
  const int b = bid / (3 * npb);
  const int px = pxb * TPBK + threadIdx.x;
  const int w = px % W, h = px / W;
  const float* xb = x + (size_t)b * HW * CI;
  const float* wj = wP + (size_t)jg * CI * 9 * 8;

  float acc[6];
#pragma unroll
  for (int u = 0; u < 6; u++) acc[u] = boff[jg * 6 + u];

#pragma unroll 1
  for (int t = 0; t < 9; t++) {
    int yy = h - 1 + t / 3, xx = w - 1 + t % 3;
    bool vld = (yy >= 0 && yy < H && xx >= 0 && xx < W);
    int a = vld ? (yy * W + xx) : 0;
    const float* xp = xb + (size_t)a * CI;
    const float* wt = wj + t * 8;
#pragma unroll 4
    for (int cg = 0; cg < CI / 4; cg++) {
      float4 v = *(const float4*)(xp + cg * 4);
      float s0 = vld ? v.x : 0.f;
      float s1 = vld ? v.y : 0.f;
      float s2 = vld ? v.z : 0.f;
      float s3 = vld ? v.w : 0.f;
      const float* w0 = wt + (size_t)cg * 4 * 72;
#pragma unroll
      for (int u = 0; u < 6; u++) {
        float a0 = fmaf(s0, w0[u], acc[u]);
        float a1 = fmaf(s1, w0[72 + u], a0);
        float a2 = fmaf(s2, w0[144 + u], a1);
        acc[u] = fmaf(s3, w0[216 + u], a2);
      }
    }
  }
#pragma unroll
  for (int u = 0; u < 6; u++)
    off[((size_t)b * 18 + jg * 6 + u) * HW + px] = acc[u];
}

// ---------------------------------------------------------------------------
// dfc_lds (L1-L4): two-phase deform conv, 64-pixel tile per block, TPB=256.
// Phase B: thread=(pixel,slice), coalesced float4 corner gathers -> LDS.
// Phase C: thread=(pixel, wave og), ds_read_b128 + s_load weights.
// Per-tap double-buffered LDS, 1 barrier per tap.
// ---------------------------------------------------------------------------
template<int CI, int CO, int OGB>
__global__ __launch_bounds__(TPB) void dfc_lds(
    const float* __restrict__ x, const float* __restrict__ off,
    const float* __restrict__ wP,   // [9*CI][CO]
    float* __restrict__ out, int B, int H, int W) {
  constexpr int S = CI / 4;            // channel slices
  constexpr int P = 64;                // pixels per block
  constexpr int COG = CO / (4 * OGB);  // out channels per wave
  constexpr int TPT = (P * S) / TPB;   // gather tasks per thread per tap
  constexpr int ROWD = P * 4 + 4;      // dwords per slice row (pad 4)

  __shared__ float s_off[18 * P];
  __shared__ float s_samp[2][S * ROWD];

  const int HW = H * W;
  const int npb = HW / P;
  const int bid = xcd_swz(blockIdx.x, gridDim.x);
  const int ogb = bid % OGB;
  const int pxb = (bid / OGB) % npb;
  const int b = bid / (OGB * npb);
  const int px0 = pxb * P;
  const int tid = threadIdx.x;
  const float* xb = x + (size_t)b * HW * CI;

  // stage this tile's offsets
  for (int t = tid; t < 18 * P; t += TPB) {
    int j = t / P, p = t % P;
    s_off[t] = off[((size_t)b * 18 + j) * HW + px0 + p];
  }
  __syncthreads();

  const int pc = tid & 63;            // phase-C pixel
  const int wid = tid >> 6;           // wave id
  const int ogc = (ogb * 4 + wid) * COG;

  float acc[COG];
#pragma unroll
  for (int o = 0; o < COG; o++) acc[o] = 0.f;

  float4 v00[TPT], v01[TPT], v10[TPT], v11[TPT];
  float cw00[TPT], cw01[TPT], cw10[TPT], cw11[TPT];
  int wla[TPT];

  auto issue = [&](int k) {
#pragma unroll
    for (int tt = 0; tt < TPT; tt++) {
      int task = tt * TPB + tid;
      int s = task % S, p = task / S;
      int px = px0 + p;
      int w = px % W, h = px / W;
      float dy = s_off[(2 * k) * P + p];
      float dx = s_off[(2 * k + 1) * P + p];
      float py = (float)(h - 1 + k / 3) + dy;
      float pxx = (float)(w - 1 + k % 3) + dx;
      float fy = floorf(py), fx = floorf(pxx);
      float wy = py - fy, wx = pxx - fx;
      int y0 = (int)fy, x0 = (int)fx;
      int y1 = y0 + 1, x1 = x0 + 1;
      bool vy0 = (y0 >= 0) & (y0 < H), vy1 = (y1 >= 0) & (y1 < H);
      bool vx0 = (x0 >= 0) & (x0 < W), vx1 = (x1 >= 0) & (x1 < W);
      int yc0 = min(max(y0, 0), H - 1), yc1 = min(max(y1, 0), H - 1);
      int xc0 = min(max(x0, 0), W - 1), xc1 = min(max(x1, 0), W - 1);
      cw00[tt] = (vy0 && vx0) ? (1.f - wy) * (1.f - wx) : 0.f;
      cw01[tt] = (vy0 && vx1) ? (1.f - wy) * wx : 0.f;
      cw10[tt] = (vy1 && vx0) ? wy * (1.f - wx) : 0.f;
      cw11[tt] = (vy1 && vx1) ? wy * wx : 0.f;
      v00[tt] = *(const float4*)(xb + (size_t)(yc0 * W + xc0) * CI + s * 4);
      v01[tt] = *(const float4*)(xb + (size_t)(yc0 * W + xc1) * CI + s * 4);
      v10[tt] = *(const float4*)(xb + (size_t)(yc1 * W + xc0) * CI + s * 4);
      v11[tt] = *(const float4*)(xb + (size_t)(yc1 * W + xc1) * CI + s * 4);
      wla[tt] = s * ROWD + p * 4;
    }
  };
  auto finish = [&](int buf) {
#pragma unroll
    for (int tt = 0; tt < TPT; tt++) {
      float4 sv;
      sv.x = v00[tt].x * cw00[tt] + v01[tt].x * cw01[tt]
           + v10[tt].x * cw10[tt] + v11[tt].x * cw11[tt];
      sv.y = v00[tt].y * cw00[tt] + v01[tt].y * cw01[tt]
           + v10[tt].y * cw10[tt] + v11[tt].y * cw11[tt];
      sv.z = v00[tt].z * cw00[tt] + v01[tt].z * cw01[tt]
           + v10[tt].z * cw10[tt] + v11[tt].z * cw11[tt];
      sv.w = v00[tt].w * cw00[tt] + v01[tt].w * cw01[tt]
           + v10[tt].w * cw10[tt] + v11[tt].w * cw11[tt];
      *(float4*)&s_samp[buf][wla[tt]] = sv;
    }
  };
  auto compute = [&](int k, int buf) {
#pragma unroll
    for (int s = 0; s < S; s++) {
      float4 sv4 = *(const float4*)&s_samp[buf][s * ROWD + pc * 4];
      float svj[4] = {sv4.x, sv4.y, sv4.z, sv4.w};
      const float* wr = wP + (size_t)(k * CI + s * 4) * CO + ogc;
#pragma unroll
      for (int j = 0; j < 4; j++)
#pragma unroll
        for (int o = 0; o < COG; o++)
          acc[o] = fmaf(svj[j], wr[j * CO + o], acc[o]);
    }
  };

  issue(0);
  finish(0);
  __syncthreads();
#pragma unroll 1
  for (int k = 0; k < 9; k++) {
    int buf = k & 1;
    if (k < 8) issue(k + 1);      // loads in flight under compute
    compute(k, buf);
    if (k < 8) finish(buf ^ 1);   // vmcnt wait + LDS write
    __syncthreads();
  }

  float* op = out + ((size_t)b * CO + ogc) * HW + px0 + pc;
#pragma unroll
  for (int o = 0; o < COG; o++) op[(size_t)o * HW] = acc[o];
}

// ---------------------------------------------------------------------------
// BatchNorm (training stats, y NCHW) + LeakyReLU; apply writes NHWC or NCHW.
// ---------------------------------------------------------------------------
__global__ void bn_stats_kernel(const float* __restrict__ y,
                                double* __restrict__ st,
                                int B, int C, int HW, int NB) {
  int c = blockIdx.x / NB;
  int sl = blockIdx.x % NB;
  int tid = threadIdx.x;
  double s = 0.0, s2 = 0.0;
  int HW4 = HW >> 2;
  for (int b = 0; b < B; b++) {
    const float4* p = (const float4*)(y + ((size_t)b * C + c) * HW);
    for (int i = sl * TPB + tid; i < HW4; i += NB * TPB) {
      float4 v = p[i];
      s += (double)v.x + (double)v.y + (double)v.z + (double)v.w;
      s2 += (double)v.x * v.x + (double)v.y * v.y
          + (double)v.z * v.z + (double)v.w * v.w;
    }
  }
  __shared__ double rs[TPB], rq[TPB];
  rs[tid] = s;
  rq[tid] = s2;
  __syncthreads();
  for (int o = TPB / 2; o > 0; o >>= 1) {
    if (tid < o) { rs[tid] += rs[tid + o]; rq[tid] += rq[tid + o]; }
    __syncthreads();
  }
  if (tid == 0) {
    atomicAdd(&st[2 * c], rs[0]);
    atomicAdd(&st[2 * c + 1], rq[0]);
  }
}

__global__ void bn_finalize_kernel(const double* __restrict__ st,
                                   const float* __restrict__ g,
                                   const float* __restrict__ bb,
                                   float* __restrict__ ss, int C, int N) {
  int c = threadIdx.x;
  if (c >= C) return;
  double mean = st[2 * c] / N;
  double var = st[2 * c + 1] / N - mean * mean;
  float inv = (float)(1.0 / sqrt(var + 1e-5));
  float sc = g[c] * inv;
  ss[c] = sc;
  ss[C + c] = bb[c] - (float)mean * sc;
}

// NCHW -> NCHW (final output)
__global__ void bn_apply_kernel(const float* __restrict__ y,
                                const float* __restrict__ ss,
                                float* __restrict__ out, int C, int HW, int n) {
  int i = blockIdx.x * TPB + threadIdx.x;
  if (i >= n) return;
  int c = (i / HW) % C;
  float v = fmaf(y[i], ss[c], ss[C + c]);
  out[i] = v > 0.f ? v : 0.01f * v;
}

// NCHW -> NHWC (no pool; L3)
__global__ void bn_apply_nhwc_kernel(const float* __restrict__ y,
                                     const float* __restrict__ ss,
                                     float* __restrict__ out,
                                     int C, int H, int W, int n) {
  int i = blockIdx.x * TPB + threadIdx.x;
  if (i >= n) return;
  int c = i % C;
  int pix = i / C;
  int w = pix % W;
  int h = (pix / W) % H;
  int b = pix / (W * H);
  float v = fmaf(y[(((size_t)b * C + c) * H + h) * W + w], ss[c], ss[C + c]);
  out[i] = v > 0.f ? v : 0.01f * v;
}

// NCHW -> 2x2 maxpool -> NHWC (L0,L1,L2)
__global__ void bn_apply_pool_nhwc_kernel(const float* __restrict__ y,
                                          const float* __restrict__ ss,
                                          float* __restrict__ out,
                                          int C, int H, int W, int n) {
  int i = blockIdx.x * TPB + threadIdx.x;
  if (i >= n) return;
  int Wp = W >> 1, Hp = H >> 1;
  int c = i % C;
  int pw = (i / C) % Wp;
  int ph = (i / C / Wp) % Hp;
  int b = i / (C * Wp * Hp);
  const float* yp = y + (((size_t)b * C + c) * H + 2 * ph) * W + 2 * pw;
  float sc = ss[c], sh = ss[C + c];
  float v0 = fmaf(yp[0], sc, sh);     v0 = v0 > 0.f ? v0 : 0.01f * v0;
  float v1 = fmaf(yp[1], sc, sh);     v1 = v1 > 0.f ? v1 : 0.01f * v1;
  float v2 = fmaf(yp[W], sc, sh);     v2 = v2 > 0.f ? v2 : 0.01f * v2;
  float v3 = fmaf(yp[W + 1], sc, sh); v3 = v3 > 0.f ? v3 : 0.01f * v3;
  out[i] = fmaxf(fmaxf(v0, v1), fmaxf(v2, v3));
}

extern "C" void kernel_launch(void* const* d_in, const int* in_sizes, int n_in,
                              void* d_out, int out_size, void* d_ws, size_t ws_size,
                              hipStream_t stream) {
  const float* x = (const float*)d_in[0];
  const float *woff[5], *boff[5], *wm[5], *g[5], *bb[5];
  for (int i = 0; i < 5; i++) {
    woff[i] = (const float*)d_in[1 + 5 * i + 0];
    boff[i] = (const float*)d_in[1 + 5 * i + 1];
    wm[i]   = (const float*)d_in[1 + 5 * i + 2];
    g[i]    = (const float*)d_in[1 + 5 * i + 3];
    bb[i]   = (const float*)d_in[1 + 5 * i + 4];
  }

  const size_t need =
      (size_t)(16777216 + 4718592 + 4194304 + 2097152 + PACK_FLOATS) * 4 + 1280 + 640;
  if (ws_size < need) return;

  float* conv_buf = (float*)d_ws;          // NCHW conv outputs (up to 67 MB)
  float* off_buf = conv_buf + 16777216;    // offsets [b][18][HW]
  float* xa = off_buf + 4718592;           // x1 / x3 (NHWC)
  float* xb2 = xa + 4194304;               // x2 / x4 (NHWC)
  float* wpk = xb2 + 2097152;              // packed weights
  double* st = (double*)(wpk + PACK_FLOATS);
  float* ss = (float*)(st + 160);

  const int B = 8;

  {
    PackSrc psrc;
    for (int i = 0; i < 5; i++) { psrc.p[i] = wm[i]; psrc.p[5 + i] = woff[i]; }
    pack_weights<<<dim3(180, 10), TPB, 0, stream>>>(psrc, wpk);
  }

  auto bn_head = [&](const float* ybuf, int C, int H, int W, int NB,
                     const float* gg, const float* bbb) {
    hipMemsetAsync(st, 0, 2 * C * sizeof(double), stream);
    bn_stats_kernel<<<C * NB, TPB, 0, stream>>>(ybuf, st, B, C, H * W, NB);
    bn_finalize_kernel<<<1, TPB, 0, stream>>>(st, gg, bbb, ss, C, B * H * W);
  };

  // ---- Layer 0: CI=1, CO=16, 128x1024, fused offsets, pool -> xa (NHWC)
  {
    const int H = 128, W = 1024;
    dfc_fused0<<<B * H * W / TPB, TPB, 0, stream>>>(
        x, wpk + OWO0, boff[0], wpk + OWM0, conv_buf, B, H, W);
    bn_head(conv_buf, 16, H, W, 32, g[0], bb[0]);
    int n = B * 16 * (H / 2) * (W / 2);
    bn_apply_pool_nhwc_kernel<<<n / TPB, TPB, 0, stream>>>(
        conv_buf, ss, xa, 16, H, W, n);
  }
  // ---- Layer 1: CI=16, CO=32, 64x512, pool -> xb2 (NHWC)
  {
    const int H = 64, W = 512;
    off_conv<16, 256><<<B * 3 * (H * W / 256), 256, 0, stream>>>(
        xa, wpk + OWO1, boff[1], off_buf, B, H, W);
    dfc_lds<16, 32, 1><<<B * (H * W / 64), TPB, 0, stream>>>(
        xa, off_buf, wpk + OWM1, conv_buf, B, H, W);
    bn_head(conv_buf, 32, H, W, 32, g[1], bb[1]);
    int n = B * 32 * (H / 2) * (W / 2);
    bn_apply_pool_nhwc_kernel<<<n / TPB, TPB, 0, stream>>>(
        conv_buf, ss, xb2, 32, H, W, n);
  }
  // ---- Layer 2: CI=32, CO=48, 32x256, pool -> xa (NHWC)
  {
    const int H = 32, W = 256;
    off_conv<32, 256><<<B * 3 * (H * W / 256), 256, 0, stream>>>(
        xb2, wpk + OWO2, boff[2], off_buf, B, H, W);
    dfc_lds<32, 48, 1><<<B * (H * W / 64), TPB, 0, stream>>>(
        xb2, off_buf, wpk + OWM2, conv_buf, B, H, W);
    bn_head(conv_buf, 48, H, W, 16, g[2], bb[2]);
    int n = B * 48 * (H / 2) * (W / 2);
    bn_apply_pool_nhwc_kernel<<<n / TPB, TPB, 0, stream>>>(
        conv_buf, ss, xa, 48, H, W, n);
  }
  // ---- Layer 3: CI=48, CO=64, 16x128, no pool -> xb2 (NHWC)
  {
    const int H = 16, W = 128;
    off_conv<48, 64><<<B * 3 * (H * W / 64), 64, 0, stream>>>(
        xa, wpk + OWO3, boff[3], off_buf, B, H, W);
    dfc_lds<48, 64, 2><<<B * (H * W / 64) * 2, TPB, 0, stream>>>(
        xa, off_buf, wpk + OWM3, conv_buf, B, H, W);
    bn_head(conv_buf, 64, H, W, 8, g[3], bb[3]);
    int n = B * 64 * H * W;
    bn_apply_nhwc_kernel<<<n / TPB, TPB, 0, stream>>>(
        conv_buf, ss, xb2, 64, H, W, n);
  }
  // ---- Layer 4: CI=64, CO=80, 16x128, no pool -> d_out (NCHW)
  {
    const int H = 16, W = 128;
    off_conv<64, 64><<<B * 3 * (H * W / 64), 64, 0, stream>>>(
        xb2, wpk + OWO4, boff[4], off_buf, B, H, W);
    dfc_lds<64, 80, 2><<<B * (H * W / 64) * 2, TPB, 0, stream>>>(
        xb2, off_buf, wpk + OWM4, conv_buf, B, H, W);
    bn_head(conv_buf, 80, H, W, 8, g[4], bb[4]);
    int n = B * 80 * H * W;
    bn_apply_kernel<<<n / TPB, TPB, 0, stream>>>(
        conv_buf, ss, (float*)d_out, 80, H * W, n);
  }
}

// Round 10
// 492.176 us; speedup vs baseline: 3.2337x; 3.2337x over previous
//
#include <hip/hip_runtime.h>
#include <math.h>

#define TPB 256

// ---------------------------------------------------------------------------
// Geometry:
//   x: [8, 1, 128, 1024] f32
//   L0: CI=1,  CO=16, 128x1024, pool -> 64x512   (fused offsets)
//   L1: CI=16, CO=32, 64x512,   pool -> 32x256
//   L2: CI=32, CO=48, 32x256,   pool -> 16x128
//   L3: CI=48, CO=64, 16x128,   no pool
//   L4: CI=64, CO=80, 16x128,   no pool -> d_out
//
// R10 = R8 base (proven 562us) + og-merge on big layers: L1 OGC 2->1
// (acc[32]), L2 OGC 3->2 (acc[24]) — halves/thirds the gather re-issue,
// which R8's counters showed as the limiter (VALUBusy 20%, HBM 2%,
// FETCH L2-resident => gather-issue bound). L3/L4 keep OGC=4/5 for
// occupancy on their tiny grids.
// R9 lesson (dfc_lds, VGPR=256, 2.4GB scratch): keeping >24 float4-equiv
// live values crosses the spill cliff — no software-pipelined reg arrays.
// Kept: NHWC activations, wave-uniform s_load packed weights, XCD swizzle,
// no launch_bounds min-wave cap, bounded unrolls.
// ---------------------------------------------------------------------------

// Packed-weight workspace offsets (floats)
#define OWM0 0
#define OWM1 144
#define OWM2 4752
#define OWM3 18576
#define OWM4 46224
#define OWO0 92304
#define OWO1 92484
#define OWO2 95940
#define OWO3 102852
#define OWO4 113220
#define PACK_FLOATS 131072

struct PackSrc { const float* p[10]; };  // 0-4: wmain, 5-9: woff

__global__ void pack_weights(PackSrc s, float* __restrict__ dst) {
  int seg = blockIdx.y;
  int idx = blockIdx.x * TPB + threadIdx.x;
  int CI, CO, ow;
  if (seg < 5) {
    if (seg == 0)      { CI = 1;  CO = 16; ow = OWM0; }
    else if (seg == 1) { CI = 16; CO = 32; ow = OWM1; }
    else if (seg == 2) { CI = 32; CO = 48; ow = OWM2; }
    else if (seg == 3) { CI = 48; CO = 64; ow = OWM3; }
    else               { CI = 64; CO = 80; ow = OWM4; }
    int n = 9 * CI * CO;
    if (idx >= n) return;
    int o = idx % CO, rest = idx / CO;
    int c = rest % CI, k = rest / CI;
    dst[ow + idx] = s.p[seg][((size_t)o * CI + c) * 9 + k];
  } else if (seg == 5) {
    if (idx >= 180) return;
    int j = idx % 20, t = idx / 20;
    dst[OWO0 + idx] = (j < 18) ? s.p[5][j * 9 + t] : 0.f;
  } else {
    if (seg == 6)      { CI = 16; ow = OWO1; }
    else if (seg == 7) { CI = 32; ow = OWO2; }
    else if (seg == 8) { CI = 48; ow = OWO3; }
    else               { CI = 64; ow = OWO4; }
    int n = 3 * CI * 9 * 8;
    if (idx >= n) return;
    int u = idx % 8, r = idx / 8;
    int t = r % 9, c = (r / 9) % CI, jg = r / (9 * CI);
    dst[ow + idx] = (u < 6) ? s.p[seg][((size_t)(jg * 6 + u) * CI + c) * 9 + t] : 0.f;
  }
}

// XCD-aware swizzle: nwg % 8 == 0 at every launch site.
__device__ __forceinline__ int xcd_swz(int bid, int nwg) {
  return (bid & 7) * (nwg >> 3) + (bid >> 3);
}

// ---------------------------------------------------------------------------
// L0: CI=1 (NCHW==NHWC) -> fused offsets + deform conv, out NCHW.
// ---------------------------------------------------------------------------
__global__ __launch_bounds__(TPB) void dfc_fused0(
    const float* __restrict__ x, const float* __restrict__ woP,   // [9][20]
    const float* __restrict__ boff, const float* __restrict__ wmP, // [9][16]
    float* __restrict__ out, int B, int H, int W) {
  const int idx = xcd_swz(blockIdx.x, gridDim.x) * TPB + threadIdx.x;
  const int HW = H * W;
  const int w = idx % W;
  const int h = (idx / W) % H;
  const int b = idx / HW;
  const float* xp = x + (size_t)b * HW;

  float xv[9];
#pragma unroll
  for (int t = 0; t < 9; t++) {
    int yy = h - 1 + t / 3, xx = w - 1 + t % 3;
    xv[t] = (yy >= 0 && yy < H && xx >= 0 && xx < W) ? xp[yy * W + xx] : 0.f;
  }

  float offv[18];
#pragma unroll
  for (int j = 0; j < 18; j++) offv[j] = boff[j];
#pragma unroll
  for (int t = 0; t < 9; t++) {
    const float* wr = &woP[t * 20];
#pragma unroll
    for (int j = 0; j < 18; j++) offv[j] = fmaf(xv[t], wr[j], offv[j]);
  }

  float acc[16];
#pragma unroll
  for (int o = 0; o < 16; o++) acc[o] = 0.f;

#pragma unroll
  for (int k = 0; k < 9; k++) {
    float py = (float)(h - 1 + k / 3) + offv[2 * k];
    float px = (float)(w - 1 + k % 3) + offv[2 * k + 1];
    float fy = floorf(py), fx = floorf(px);
    float wy = py - fy, wx = px - fx;
    int y0 = (int)fy, x0 = (int)fx;
    int y1 = y0 + 1, x1 = x0 + 1;
    bool vy0 = (y0 >= 0) & (y0 < H), vy1 = (y1 >= 0) & (y1 < H);
    bool vx0 = (x0 >= 0) & (x0 < W), vx1 = (x1 >= 0) & (x1 < W);
    int yc0 = min(max(y0, 0), H - 1), yc1 = min(max(y1, 0), H - 1);
    int xc0 = min(max(x0, 0), W - 1), xc1 = min(max(x1, 0), W - 1);
    float w00 = (vy0 && vx0) ? (1.f - wy) * (1.f - wx) : 0.f;
    float w01 = (vy0 && vx1) ? (1.f - wy) * wx : 0.f;
    float w10 = (vy1 && vx0) ? wy * (1.f - wx) : 0.f;
    float w11 = (vy1 && vx1) ? wy * wx : 0.f;
    float sv = xp[yc0 * W + xc0] * w00 + xp[yc0 * W + xc1] * w01
             + xp[yc1 * W + xc0] * w10 + xp[yc1 * W + xc1] * w11;
    const float* wr = &wmP[k * 16];
#pragma unroll
    for (int o = 0; o < 16; o++) acc[o] = fmaf(sv, wr[o], acc[o]);
  }

  float* op = out + (size_t)b * 16 * HW + h * W + w;
#pragma unroll
  for (int o = 0; o < 16; o++) op[(size_t)o * HW] = acc[o];
}

// ---------------------------------------------------------------------------
// Offset conv (L1-L4): x NHWC, per tap CI/4 float4 loads, s_load weights.
// ---------------------------------------------------------------------------
template<int CI, int TPBK>
__global__ __launch_bounds__(TPBK) void off_conv(
    const float* __restrict__ x, const float* __restrict__ wP,
    const float* __restrict__ boff, float* __restrict__ off,
    int B, int H, int W) {
  const int HW = H * W;
  const int npb = HW / TPBK;
  const int bid = xcd_swz(blockIdx.x, gridDim.x);
  const int pxb = bid % npb;
  const int jg = (bid / npb) % 3;
  const int b = bid / (3 * npb);
  const int px = pxb * TPBK + threadIdx.x;
  const int w = px % W, h = px / W;
  const float* xb = x + (size_t)b * HW * CI;
  const float* wj = wP + (size_t)jg * CI * 9 * 8;

  float acc[6];
#pragma unroll
  for (int u = 0; u < 6; u++) acc[u] = boff[jg * 6 + u];

#pragma unroll 1
  for (int t = 0; t < 9; t++) {
    int yy = h - 1 + t / 3, xx = w - 1 + t % 3;
    bool vld = (yy >= 0 && yy < H && xx >= 0 && xx < W);
    int a = vld ? (yy * W + xx) : 0;
    const float* xp = xb + (size_t)a * CI;
    const float* wt = wj + t * 8;
#pragma unroll 4
    for (int cg = 0; cg < CI / 4; cg++) {
      float4 v = *(const float4*)(xp + cg * 4);
      float s0 = vld ? v.x : 0.f;
      float s1 = vld ? v.y : 0.f;
      float s2 = vld ? v.z : 0.f;
      float s3 = vld ? v.w : 0.f;
      const float* w0 = wt + (size_t)cg * 4 * 72;
#pragma unroll
      for (int u = 0; u < 6; u++) {
        float a0 = fmaf(s0, w0[u], acc[u]);
        float a1 = fmaf(s1, w0[72 + u], a0);
        float a2 = fmaf(s2, w0[144 + u], a1);
        acc[u] = fmaf(s3, w0[216 + u], a2);
      }
    }
  }
#pragma unroll
  for (int u = 0; u < 6; u++)
    off[((size_t)b * 18 + jg * 6 + u) * HW + px] = acc[u];
}

// ---------------------------------------------------------------------------
// Deform conv (L1-L4), og-split, x NHWC: per k-tap x c-group = 4 float4
// corner loads. Out NCHW. acc[CO/OGC]. Weights wave-uniform s_load.
// ---------------------------------------------------------------------------
template<int CI, int CO, int OGC, int TPBK>
__global__ __launch_bounds__(TPBK) void dfc_og(
    const float* __restrict__ x, const float* __restrict__ off,
    const float* __restrict__ wP, float* __restrict__ out,
    int B, int H, int W) {
  constexpr int COG = CO / OGC;
  const int HW = H * W;
  const int npb = HW / TPBK;
  const int bid = xcd_swz(blockIdx.x, gridDim.x);
  const int og = bid % OGC;
  const int pxb = (bid / OGC) % npb;
  const int b = bid / (OGC * npb);
  const int px = pxb * TPBK + threadIdx.x;
  const int w = px % W, h = px / W;
  const float* xb = x + (size_t)b * HW * CI;   // NHWC

  float offv[18];
  const float* ob = off + (size_t)b * 18 * HW + px;
#pragma unroll
  for (int j = 0; j < 18; j++) offv[j] = ob[(size_t)j * HW];

  float acc[COG];
#pragma unroll
  for (int o = 0; o < COG; o++) acc[o] = 0.f;

#pragma unroll
  for (int k = 0; k < 9; k++) {
    float py = (float)(h - 1 + k / 3) + offv[2 * k];
    float pxx = (float)(w - 1 + k % 3) + offv[2 * k + 1];
    float fy = floorf(py), fx = floorf(pxx);
    float wy = py - fy, wx = pxx - fx;
    int y0 = (int)fy, x0 = (int)fx;
    int y1 = y0 + 1, x1 = x0 + 1;
    bool vy0 = (y0 >= 0) & (y0 < H), vy1 = (y1 >= 0) & (y1 < H);
    bool vx0 = (x0 >= 0) & (x0 < W), vx1 = (x1 >= 0) & (x1 < W);
    int yc0 = min(max(y0, 0), H - 1), yc1 = min(max(y1, 0), H - 1);
    int xc0 = min(max(x0, 0), W - 1), xc1 = min(max(x1, 0), W - 1);
    float w00 = (vy0 && vx0) ? (1.f - wy) * (1.f - wx) : 0.f;
    float w01 = (vy0 && vx1) ? (1.f - wy) * wx : 0.f;
    float w10 = (vy1 && vx0) ? wy * (1.f - wx) : 0.f;
    float w11 = (vy1 && vx1) ? wy * wx : 0.f;
    const float* p00 = xb + (size_t)(yc0 * W + xc0) * CI;
    const float* p01 = xb + (size_t)(yc0 * W + xc1) * CI;
    const float* p10 = xb + (size_t)(yc1 * W + xc0) * CI;
    const float* p11 = xb + (size_t)(yc1 * W + xc1) * CI;
#pragma unroll 2
    for (int cg = 0; cg < CI / 4; cg++) {
      float4 v00 = *(const float4*)(p00 + cg * 4);
      float4 v01 = *(const float4*)(p01 + cg * 4);
      float4 v10 = *(const float4*)(p10 + cg * 4);
      float4 v11 = *(const float4*)(p11 + cg * 4);
      float s0 = v00.x * w00 + v01.x * w01 + v10.x * w10 + v11.x * w11;
      float s1 = v00.y * w00 + v01.y * w01 + v10.y * w10 + v11.y * w11;
      float s2 = v00.z * w00 + v01.z * w01 + v10.z * w10 + v11.z * w11;
      float s3 = v00.w * w00 + v01.w * w01 + v10.w * w10 + v11.w * w11;
      const float* wr = wP + (size_t)(k * CI + cg * 4) * CO + og * COG;
#pragma unroll
      for (int o = 0; o < COG; o++) {
        float a0 = fmaf(s0, wr[o], acc[o]);
        float a1 = fmaf(s1, wr[CO + o], a0);
        float a2 = fmaf(s2, wr[2 * CO + o], a1);
        acc[o] = fmaf(s3, wr[3 * CO + o], a2);
      }
    }
  }

  float* op = out + ((size_t)b * CO + og * COG) * HW + px;
#pragma unroll
  for (int o = 0; o < COG; o++) op[(size_t)o * HW] = acc[o];
}

// ---------------------------------------------------------------------------
// BatchNorm (training stats, y NCHW) + LeakyReLU; apply writes NHWC or NCHW.
// ---------------------------------------------------------------------------
__global__ void bn_stats_kernel(const float* __restrict__ y,
                                double* __restrict__ st,
                                int B, int C, int HW, int NB) {
  int c = blockIdx.x / NB;
  int sl = blockIdx.x % NB;
  int tid = threadIdx.x;
  double s = 0.0, s2 = 0.0;
  int HW4 = HW >> 2;
  for (int b = 0; b < B; b++) {
    const float4* p = (const float4*)(y + ((size_t)b * C + c) * HW);
    for (int i = sl * TPB + tid; i < HW4; i += NB * TPB) {
      float4 v = p[i];
      s += (double)v.x + (double)v.y + (double)v.z + (double)v.w;
      s2 += (double)v.x * v.x + (double)v.y * v.y
          + (double)v.z * v.z + (double)v.w * v.w;
    }
  }
  __shared__ double rs[TPB], rq[TPB];
  rs[tid] = s;
  rq[tid] = s2;
  __syncthreads();
  for (int o = TPB / 2; o > 0; o >>= 1) {
    if (tid < o) { rs[tid] += rs[tid + o]; rq[tid] += rq[tid + o]; }
    __syncthreads();
  }
  if (tid == 0) {
    atomicAdd(&st[2 * c], rs[0]);
    atomicAdd(&st[2 * c + 1], rq[0]);
  }
}

__global__ void bn_finalize_kernel(const double* __restrict__ st,
                                   const float* __restrict__ g,
                                   const float* __restrict__ bb,
                                   float* __restrict__ ss, int C, int N) {
  int c = threadIdx.x;
  if (c >= C) return;
  double mean = st[2 * c] / N;
  double var = st[2 * c + 1] / N - mean * mean;
  float inv = (float)(1.0 / sqrt(var + 1e-5));
  float sc = g[c] * inv;
  ss[c] = sc;
  ss[C + c] = bb[c] - (float)mean * sc;
}

// NCHW -> NCHW (final output)
__global__ void bn_apply_kernel(const float* __restrict__ y,
                                const float* __restrict__ ss,
                                float* __restrict__ out, int C, int HW, int n) {
  int i = blockIdx.x * TPB + threadIdx.x;
  if (i >= n) return;
  int c = (i / HW) % C;
  float v = fmaf(y[i], ss[c], ss[C + c]);
  out[i] = v > 0.f ? v : 0.01f * v;
}

// NCHW -> NHWC (no pool; L3)
__global__ void bn_apply_nhwc_kernel(const float* __restrict__ y,
                                     const float* __restrict__ ss,
                                     float* __restrict__ out,
                                     int C, int H, int W, int n) {
  int i = blockIdx.x * TPB + threadIdx.x;
  if (i >= n) return;
  int c = i % C;
  int pix = i / C;
  int w = pix % W;
  int h = (pix / W) % H;
  int b = pix / (W * H);
  float v = fmaf(y[(((size_t)b * C + c) * H + h) * W + w], ss[c], ss[C + c]);
  out[i] = v > 0.f ? v : 0.01f * v;
}

// NCHW -> 2x2 maxpool -> NHWC (L0,L1,L2)
__global__ void bn_apply_pool_nhwc_kernel(const float* __restrict__ y,
                                          const float* __restrict__ ss,
                                          float* __restrict__ out,
                                          int C, int H, int W, int n) {
  int i = blockIdx.x * TPB + threadIdx.x;
  if (i >= n) return;
  int Wp = W >> 1, Hp = H >> 1;
  int c = i % C;
  int pw = (i / C) % Wp;
  int ph = (i / C / Wp) % Hp;
  int b = i / (C * Wp * Hp);
  const float* yp = y + (((size_t)b * C + c) * H + 2 * ph) * W + 2 * pw;
  float sc = ss[c], sh = ss[C + c];
  float v0 = fmaf(yp[0], sc, sh);     v0 = v0 > 0.f ? v0 : 0.01f * v0;
  float v1 = fmaf(yp[1], sc, sh);     v1 = v1 > 0.f ? v1 : 0.01f * v1;
  float v2 = fmaf(yp[W], sc, sh);     v2 = v2 > 0.f ? v2 : 0.01f * v2;
  float v3 = fmaf(yp[W + 1], sc, sh); v3 = v3 > 0.f ? v3 : 0.01f * v3;
  out[i] = fmaxf(fmaxf(v0, v1), fmaxf(v2, v3));
}

extern "C" void kernel_launch(void* const* d_in, const int* in_sizes, int n_in,
                              void* d_out, int out_size, void* d_ws, size_t ws_size,
                              hipStream_t stream) {
  const float* x = (const float*)d_in[0];
  const float *woff[5], *boff[5], *wm[5], *g[5], *bb[5];
  for (int i = 0; i < 5; i++) {
    woff[i] = (const float*)d_in[1 + 5 * i + 0];
    boff[i] = (const float*)d_in[1 + 5 * i + 1];
    wm[i]   = (const float*)d_in[1 + 5 * i + 2];
    g[i]    = (const float*)d_in[1 + 5 * i + 3];
    bb[i]   = (const float*)d_in[1 + 5 * i + 4];
  }

  const size_t need =
      (size_t)(16777216 + 4718592 + 4194304 + 2097152 + PACK_FLOATS) * 4 + 1280 + 640;
  if (ws_size < need) return;

  float* conv_buf = (float*)d_ws;          // NCHW conv outputs (up to 67 MB)
  float* off_buf = conv_buf + 16777216;    // offsets [b][18][HW]
  float* xa = off_buf + 4718592;           // x1 / x3 (NHWC)
  float* xb2 = xa + 4194304;               // x2 / x4 (NHWC)
  float* wpk = xb2 + 2097152;              // packed weights
  double* st = (double*)(wpk + PACK_FLOATS);
  float* ss = (float*)(st + 160);

  const int B = 8;

  {
    PackSrc psrc;
    for (int i = 0; i < 5; i++) { psrc.p[i] = wm[i]; psrc.p[5 + i] = woff[i]; }
    pack_weights<<<dim3(180, 10), TPB, 0, stream>>>(psrc, wpk);
  }

  auto bn_head = [&](const float* ybuf, int C, int H, int W, int NB,
                     const float* gg, const float* bbb) {
    hipMemsetAsync(st, 0, 2 * C * sizeof(double), stream);
    bn_stats_kernel<<<C * NB, TPB, 0, stream>>>(ybuf, st, B, C, H * W, NB);
    bn_finalize_kernel<<<1, TPB, 0, stream>>>(st, gg, bbb, ss, C, B * H * W);
  };

  // ---- Layer 0: CI=1, CO=16, 128x1024, fused offsets, pool -> xa (NHWC)
  {
    const int H = 128, W = 1024;
    dfc_fused0<<<B * H * W / TPB, TPB, 0, stream>>>(
        x, wpk + OWO0, boff[0], wpk + OWM0, conv_buf, B, H, W);
    bn_head(conv_buf, 16, H, W, 32, g[0], bb[0]);
    int n = B * 16 * (H / 2) * (W / 2);
    bn_apply_pool_nhwc_kernel<<<n / TPB, TPB, 0, stream>>>(
        conv_buf, ss, xa, 16, H, W, n);
  }
  // ---- Layer 1: CI=16, CO=32, 64x512, pool -> xb2 (NHWC), OGC=1
  {
    const int H = 64, W = 512;
    off_conv<16, 256><<<B * 3 * (H * W / 256), 256, 0, stream>>>(
        xa, wpk + OWO1, boff[1], off_buf, B, H, W);
    dfc_og<16, 32, 1, 256><<<B * (H * W / 256), 256, 0, stream>>>(
        xa, off_buf, wpk + OWM1, conv_buf, B, H, W);
    bn_head(conv_buf, 32, H, W, 32, g[1], bb[1]);
    int n = B * 32 * (H / 2) * (W / 2);
    bn_apply_pool_nhwc_kernel<<<n / TPB, TPB, 0, stream>>>(
        conv_buf, ss, xb2, 32, H, W, n);
  }
  // ---- Layer 2: CI=32, CO=48, 32x256, pool -> xa (NHWC), OGC=2
  {
    const int H = 32, W = 256;
    off_conv<32, 256><<<B * 3 * (H * W / 256), 256, 0, stream>>>(
        xb2, wpk + OWO2, boff[2], off_buf, B, H, W);
    dfc_og<32, 48, 2, 256><<<B * (H * W / 256) * 2, 256, 0, stream>>>(
        xb2, off_buf, wpk + OWM2, conv_buf, B, H, W);
    bn_head(conv_buf, 48, H, W, 16, g[2], bb[2]);
    int n = B * 48 * (H / 2) * (W / 2);
    bn_apply_pool_nhwc_kernel<<<n / TPB, TPB, 0, stream>>>(
        conv_buf, ss, xa, 48, H, W, n);
  }
  // ---- Layer 3: CI=48, CO=64, 16x128, no pool -> xb2 (NHWC), OGC=4
  {
    const int H = 16, W = 128;
    off_conv<48, 64><<<B * 3 * (H * W / 64), 64, 0, stream>>>(
        xa, wpk + OWO3, boff[3], off_buf, B, H, W);
    dfc_og<48, 64, 4, 64><<<B * (H * W / 64) * 4, 64, 0, stream>>>(
        xa, off_buf, wpk + OWM3, conv_buf, B, H, W);
    bn_head(conv_buf, 64, H, W, 8, g[3], bb[3]);
    int n = B * 64 * H * W;
    bn_apply_nhwc_kernel<<<n / TPB, TPB, 0, stream>>>(
        conv_buf, ss, xb2, 64, H, W, n);
  }
  // ---- Layer 4: CI=64, CO=80, 16x128, no pool -> d_out (NCHW), OGC=5
  {
    const int H = 16, W = 128;
    off_conv<64, 64><<<B * 3 * (H * W / 64), 64, 0, stream>>>(
        xb2, wpk + OWO4, boff[4], off_buf, B, H, W);
    dfc_og<64, 80, 5, 64><<<B * (H * W / 64) * 5, 64, 0, stream>>>(
        xb2, off_buf, wpk + OWM4, conv_buf, B, H, W);
    bn_head(conv_buf, 80, H, W, 8, g[4], bb[4]);
    int n = B * 80 * H * W;
    bn_apply_kernel<<<n / TPB, TPB, 0, stream>>>(
        conv_buf, ss, (float*)d_out, 80, H * W, n);
  }
}